// Round 19
// baseline (231.785 us; speedup 1.0000x reference)
//
#include <hip/hip_runtime.h>

#define B_ 8
#define E_ 32768
#define N_ 4096
#define D_ 64
#define R_ 500
#define L_ 3
#define EPS_ 1e-5f

#define SEG0 256
#define SEG1 ((R_+B_)*64)
#define SEG2 (L_*12288)
#define SEG3 (L_*8192)
#define SEG4 (B_*N_*D_)
#define SEG5 (2*B_*N_)

typedef short bf16x8 __attribute__((ext_vector_type(8)));
typedef float f32x4 __attribute__((ext_vector_type(4)));

__device__ __forceinline__ float sigm(float x){ return 1.0f/(1.0f+__expf(-x)); }
__device__ __forceinline__ unsigned short f2bf(float x){
  unsigned u = __float_as_uint(x);
  u += 0x7fffu + ((u>>16)&1u);
  return (unsigned short)(u>>16);
}
__device__ __forceinline__ bf16x8 pk8(float4 a0, float4 a1, float4 b0, float4 b1){
  bf16x8 v;
  v[0]=(short)f2bf(a0.x*b0.x); v[1]=(short)f2bf(a0.y*b0.y);
  v[2]=(short)f2bf(a0.z*b0.z); v[3]=(short)f2bf(a0.w*b0.w);
  v[4]=(short)f2bf(a1.x*b1.x); v[5]=(short)f2bf(a1.y*b1.y);
  v[6]=(short)f2bf(a1.z*b1.z); v[7]=(short)f2bf(a1.w*b1.w);
  return v;
}
__device__ __forceinline__ bf16x8 cv8(float4 a0, float4 a1){
  bf16x8 v;
  v[0]=(short)f2bf(a0.x); v[1]=(short)f2bf(a0.y); v[2]=(short)f2bf(a0.z); v[3]=(short)f2bf(a0.w);
  v[4]=(short)f2bf(a1.x); v[5]=(short)f2bf(a1.y); v[6]=(short)f2bf(a1.z); v[7]=(short)f2bf(a1.w);
  return v;
}

// ONE fused setup launch: w2sum/w1sum0 | betadot | Btw | Utw | h+hW1p init | deg zero.
__global__ void k_setup(const float* __restrict__ rel_table, const float* __restrict__ r_query,
                        const float* __restrict__ beta_w, const float* __restrict__ msg_w,
                        const float* __restrict__ upd_w,
                        float* __restrict__ w2sum, float* __restrict__ w1sum0,
                        float* __restrict__ bdot, float* __restrict__ qdot,
                        unsigned short* __restrict__ Btw, unsigned short* __restrict__ Utw,
                        float* __restrict__ h, float* __restrict__ hW1p,
                        int* __restrict__ degzero){
  int t = blockIdx.x*256 + threadIdx.x;
  if(t < SEG0){
    int wv = t >> 6, j = t & 63;
    if(wv < 3){
      const float* W2 = msg_w + wv*5*D_*D_ + 2*D_*D_;
      float s = 0.f;
      #pragma unroll
      for(int i=0;i<D_;i++) s += W2[i*D_+j];
      w2sum[wv*D_+j] = s;
    } else {
      const float* W1 = msg_w + 1*D_*D_;
      float s = 0.f;
      #pragma unroll
      for(int i=0;i<D_;i++) s += W1[i*D_+j];
      w1sum0[j] = s;
    }
    return;
  }
  t -= SEG0;
  if(t < SEG1){
    int item = t >> 6, j = t & 63;
    float x = (item < R_ ? rel_table[item*D_+j] : r_query[(item-R_)*D_+j]) * beta_w[j];
    #pragma unroll
    for(int off=32; off; off>>=1) x += __shfl_xor(x, off, 64);
    if(j==0){ if(item < R_) bdot[item] = x; else qdot[item-R_] = x; }
    return;
  }
  t -= SEG1;
  if(t < SEG2){
    int k = t / 12288, rem = t % 12288;
    int n = rem / 192, kk = rem % 192;
    const float* W0 = msg_w + k*5*D_*D_;
    float v = (kk<64)  ? W0[kk*64+n]
            : (kk<128) ? W0[4*D_*D_ + (kk-64)*64+n]      // W4
            :            W0[3*D_*D_ + (kk-128)*64+n];    // W3
    *(unsigned short*)((char*)Btw + k*24576 + n*384 + ((kk*2) ^ ((n&7)<<4))) = f2bf(v);
    return;
  }
  t -= SEG2;
  if(t < SEG3){
    int k = t >> 13, rem = t & 8191;
    int sel = rem >> 12, idx = rem & 4095;
    int n = idx >> 6, kk = idx & 63;
    float v;
    if(sel==0){
      int jsrc = (kk>>2) + (kk&3)*16;
      v = upd_w[k*D_*D_ + jsrc*64 + n];
    } else {
      v = (k < L_-1) ? msg_w[(k+1)*5*D_*D_ + D_*D_ + kk*64 + n] : 0.f;
    }
    *(unsigned short*)((char*)Utw + k*16384 + sel*8192 + n*128 + ((kk*2) ^ ((n&7)<<4))) = f2bf(v);
    return;
  }
  t -= SEG3;
  if(t < SEG4){
    int n = (t / D_) & (N_-1);
    int p = t & (D_-1);
    bool z = (n==0);
    h[t] = z ? 1.0f : 0.0f;
    float hv = 0.0f;
    if(z){
      int j = (p>>2) + (p&3)*16;
      const float* W1 = msg_w + 1*D_*D_;
      const float* W2 = msg_w + 2*D_*D_;
      float s1 = 0.f, s2 = 0.f;
      #pragma unroll
      for(int i=0;i<D_;i++){ s1 += W1[i*D_+j]; s2 += W2[i*D_+j]; }
      hv = s1 + s2;
    }
    hW1p[t] = hv;
    return;
  }
  t -= SEG4;
  if(t < SEG5) degzero[t] = 0;
}

// CSR build (tgt)
__global__ void k_hist(const int* __restrict__ edge_index, int* __restrict__ deg){
  int idx = blockIdx.x*256 + threadIdx.x;
  int b = idx >> 15, e = idx & (E_-1);
  int tgt = edge_index[b*2*E_ + E_ + e];
  atomicAdd(&deg[b*N_ + tgt], 1);
}
__global__ void k_scan(const int* __restrict__ deg, int* __restrict__ off,
                       int* __restrict__ cursor){
  int blk = blockIdx.x, t = threadIdx.x;
  int base = blk*N_ + t*4;
  int v0 = deg[base], v1 = deg[base+1], v2 = deg[base+2], v3 = deg[base+3];
  int s = v0+v1+v2+v3;
  int lane = t & 63, w = t >> 6;
  int x = s;
  #pragma unroll
  for(int d=1; d<64; d<<=1){
    int y = __shfl_up(x, d, 64);
    if(lane >= d) x += y;
  }
  int wave_excl = x - s;
  __shared__ int wsum[16];
  if(lane==63) wsum[w] = x;
  __syncthreads();
  int wbase = 0;
  for(int i=0;i<w;i++) wbase += wsum[i];
  int excl = wbase + wave_excl;
  off[base]   = excl;           cursor[base]   = excl;
  off[base+1] = excl+v0;        cursor[base+1] = excl+v0;
  off[base+2] = excl+v0+v1;     cursor[base+2] = excl+v0+v1;
  off[base+3] = excl+v0+v1+v2;  cursor[base+3] = excl+v0+v1+v2;
}
__global__ void k_fill(const int* __restrict__ edge_index, int* __restrict__ cursor,
                       unsigned short* __restrict__ eidlist){
  int idx = blockIdx.x*256 + threadIdx.x;
  int b = idx >> 15, e = idx & (E_-1);
  int tgt = edge_index[b*2*E_ + E_ + e];
  int pos = atomicAdd(&cursor[b*N_ + tgt], 1);
  eidlist[b*E_ + pos] = (unsigned short)e;
}

// MFMA edge kernel (R18 structure; occupancy hint 4->5 waves/EU, VGPR cap 102 >> need 64)
__global__ void __launch_bounds__(256,5) k_edge(
    const int* __restrict__ edge_index, const int* __restrict__ rels,
    const float* __restrict__ scores, const int* __restrict__ confm,
    const float* __restrict__ bdot, const float* __restrict__ qdot,
    const float* __restrict__ beta_b,
    const float* __restrict__ h, const float* __restrict__ rel_table,
    const float* __restrict__ conf, unsigned short* __restrict__ confp,
    const unsigned short* __restrict__ Btw, const float* __restrict__ msg_b,
    const float* __restrict__ hW1p, int k, unsigned short* __restrict__ wmsg){
  __shared__ __align__(16) uint4 Bsh4[1536];     // 24 KB

  const int tid = threadIdx.x, wid = tid>>6, lane = tid&63;
  const int b     = blockIdx.x & 7;              // XCD-affine batch
  const int chunk = blockIdx.x >> 3;
  const int ein_b = chunk*128 + wid*32;
  const int ebase = b*E_ + ein_b;
  const int ein   = ein_b + (lane&31);
  const int eg    = b*E_ + ein;

  {
    const uint4* src = (const uint4*)((const char*)Btw + k*24576);
    #pragma unroll
    for(int i=0;i<6;i++) Bsh4[i*256+tid] = src[i*256+tid];
  }

  int   srcv = edge_index[b*2*E_ + ein];
  int   relv = rels[eg];
  float beta = sigm(bdot[relv] + qdot[b] + beta_b[0]);
  float gv   = (confm[eg]!=0) ? sigm((scores[eg]-beta)*10.0f) : 0.5f;

  int s_m[2], r_m[2];
  #pragma unroll
  for(int mt=0;mt<2;mt++){
    s_m[mt] = __shfl(srcv, mt*16 + (lane&15));
    r_m[mt] = __shfl(relv, mt*16 + (lane&15));
  }

  bf16x8 af0[2], ar0[2];
  #pragma unroll
  for(int mt=0;mt<2;mt++){
    const float* hp = h + (size_t)(b*N_+s_m[mt])*64 + (lane>>4)*8;
    const float* rp = rel_table + (size_t)r_m[mt]*64 + (lane>>4)*8;
    float4 h0 = *(const float4*)hp, h1 = *(const float4*)(hp+4);
    float4 r0 = *(const float4*)rp, r1 = *(const float4*)(rp+4);
    af0[mt] = pk8(h0, h1, r0, r1);
    ar0[mt] = cv8(r0, r1);
  }

  // conf fragments: k==0 read f32 + publish packed; k>0 read packed; no-ws fallback f32
  bf16x8 af2[2][2];
  const int half = (ebase>>5)&1;
  uint4* cp = confp ? ((uint4*)confp + (size_t)(ebase>>6)*8*64) : (uint4*)nullptr;
  if(confp && k > 0){
    #pragma unroll
    for(int mt=0;mt<2;mt++)
      #pragma unroll
      for(int kt2=0;kt2<2;kt2++)
        af2[mt][kt2] = *(const bf16x8*)((const uint4*)cp + ((half*2+mt)*2+kt2)*64 + lane);
  } else {
    const float* cb = conf + (size_t)ebase*64;
    #pragma unroll
    for(int mt=0;mt<2;mt++)
      #pragma unroll
      for(int kt2=0;kt2<2;kt2++){
        const float* src = cb + (size_t)(mt*16 + (lane&15))*64 + kt2*32 + (lane>>4)*8;
        af2[mt][kt2] = cv8(*(const float4*)src, *(const float4*)(src+4));
      }
    if(confp){
      #pragma unroll
      for(int mt=0;mt<2;mt++)
        #pragma unroll
        for(int kt2=0;kt2<2;kt2++)
          cp[((half*2+mt)*2+kt2)*64 + lane] = *(const uint4*)&af2[mt][kt2];
    }
  }
  __syncthreads();

  f32x4 acc[2][4];
  #pragma unroll
  for(int mt=0;mt<2;mt++)
    #pragma unroll
    for(int nt=0;nt<4;nt++) acc[mt][nt] = (f32x4){0.f,0.f,0.f,0.f};

  bf16x8 af1[2], ar1[2];
  {
    bf16x8 bfr[4];
    int kbyte = (lane>>4)*16;
    #pragma unroll
    for(int nt=0;nt<4;nt++){
      int n = nt*16 + (lane&15);
      bfr[nt] = *(const bf16x8*)((const char*)Bsh4 + n*384 + (kbyte ^ ((n&7)<<4)));
    }
    #pragma unroll
    for(int mt=0;mt<2;mt++){
      const float* hp = h + (size_t)(b*N_+s_m[mt])*64 + 32 + (lane>>4)*8;
      const float* rp = rel_table + (size_t)r_m[mt]*64 + 32 + (lane>>4)*8;
      float4 h0 = *(const float4*)hp, h1 = *(const float4*)(hp+4);
      float4 r0 = *(const float4*)rp, r1 = *(const float4*)(rp+4);
      af1[mt] = pk8(h0, h1, r0, r1);
      ar1[mt] = cv8(r0, r1);
    }
    #pragma unroll
    for(int mt=0;mt<2;mt++)
      #pragma unroll
      for(int nt=0;nt<4;nt++)
        acc[mt][nt] = __builtin_amdgcn_mfma_f32_16x16x32_bf16(af0[mt], bfr[nt], acc[mt][nt], 0,0,0);
  }
  {
    bf16x8 bfr[4];
    int kbyte = 64 + (lane>>4)*16;
    #pragma unroll
    for(int nt=0;nt<4;nt++){
      int n = nt*16 + (lane&15);
      bfr[nt] = *(const bf16x8*)((const char*)Bsh4 + n*384 + (kbyte ^ ((n&7)<<4)));
    }
    #pragma unroll
    for(int mt=0;mt<2;mt++)
      #pragma unroll
      for(int nt=0;nt<4;nt++)
        acc[mt][nt] = __builtin_amdgcn_mfma_f32_16x16x32_bf16(af1[mt], bfr[nt], acc[mt][nt], 0,0,0);
  }
  #pragma unroll
  for(int kt2=0;kt2<2;kt2++){
    bf16x8 bfr[4];
    int kbyte = 128 + kt2*64 + (lane>>4)*16;
    #pragma unroll
    for(int nt=0;nt<4;nt++){
      int n = nt*16 + (lane&15);
      bfr[nt] = *(const bf16x8*)((const char*)Bsh4 + n*384 + (kbyte ^ ((n&7)<<4)));
    }
    #pragma unroll
    for(int mt=0;mt<2;mt++)
      #pragma unroll
      for(int nt=0;nt<4;nt++)
        acc[mt][nt] = __builtin_amdgcn_mfma_f32_16x16x32_bf16(af2[mt][kt2], bfr[nt], acc[mt][nt], 0,0,0);
  }
  #pragma unroll
  for(int kt3=0;kt3<2;kt3++){
    bf16x8 bfr[4];
    int kbyte = 256 + kt3*64 + (lane>>4)*16;
    #pragma unroll
    for(int nt=0;nt<4;nt++){
      int n = nt*16 + (lane&15);
      bfr[nt] = *(const bf16x8*)((const char*)Bsh4 + n*384 + (kbyte ^ ((n&7)<<4)));
    }
    #pragma unroll
    for(int mt=0;mt<2;mt++)
      #pragma unroll
      for(int nt=0;nt<4;nt++)
        acc[mt][nt] = __builtin_amdgcn_mfma_f32_16x16x32_bf16(kt3 ? ar1[mt] : ar0[mt], bfr[nt], acc[mt][nt], 0,0,0);
  }

  float mb[4];
  #pragma unroll
  for(int nt=0;nt<4;nt++) mb[nt] = msg_b[k*64 + nt*16 + (lane&15)];
  #pragma unroll
  for(int mt=0;mt<2;mt++){
    #pragma unroll
    for(int jr=0;jr<4;jr++){
      int eloc  = mt*16 + (lane>>4)*4 + jr;
      int src_e = __shfl(srcv, eloc);
      float g_e = __shfl(gv,   eloc);
      f32x4 hw = *(const f32x4*)(hW1p + (size_t)(b*N_+src_e)*64 + (lane&15)*4);
      union { unsigned short s[4]; unsigned long long q; } o;
      #pragma unroll
      for(int nt=0;nt<4;nt++){
        float v = acc[mt][nt][jr] + hw[nt] + mb[nt];
        v = fmaxf(v, 0.f) * g_e;
        o.s[nt] = f2bf(v);
      }
      *(unsigned long long*)(wmsg + (size_t)(ebase+eloc)*64 + (lane&15)*4) = o.q;
    }
  }
}

// MFMA node update (occupancy hint 2->4 waves/EU, VGPR cap 128 >> need ~64)
__global__ void __launch_bounds__(256,4) k_update(
    const unsigned short* __restrict__ wmsg,
    const int* __restrict__ off, const int* __restrict__ deg,
    const unsigned short* __restrict__ eidlist,
    const unsigned short* __restrict__ Utw,
    const float* __restrict__ upd_b, const float* __restrict__ ln_g,
    const float* __restrict__ ln_b, const float* __restrict__ w2sum,
    int k, float* __restrict__ h, float* __restrict__ hW1p,
    float* __restrict__ out){
  __shared__ __align__(16) uint4 Ush4[512];
  __shared__ __align__(16) uint4 Wsh4[512];
  __shared__ __align__(16) unsigned short Ysh[4*1024];

  const int tid = threadIdx.x, wid = tid>>6, lane = tid&63;
  const int b  = blockIdx.x & 7;
  const int nb = (blockIdx.x >> 3) * 64;

  {
    const uint4* src = (const uint4*)((const char*)Utw + (size_t)k*16384);
    Ush4[tid]     = src[tid];
    Ush4[256+tid] = src[256+tid];
    Wsh4[tid]     = src[512+tid];
    Wsh4[256+tid] = src[768+tid];
  }

  const int nd    = nb + wid*16 + (lane&15);
  const int cbase = b*N_ + nd;
  int o0 = off[cbase], dg = deg[cbase];
  int mdg = dg;
  #pragma unroll
  for(int o=1;o<16;o<<=1) mdg = max(mdg, __shfl_xor(mdg, o, 64));

  const unsigned short* el = eidlist + b*E_ + o0;
  const unsigned short* wb = wmsg + (size_t)b*E_*64;
  const int cb = (lane>>4)*8;

  float a0[8], a1[8];
  #pragma unroll
  for(int u=0;u<8;u++){ a0[u]=0.f; a1[u]=0.f; }

  for(int c=0; c<mdg; c+=8){
    int e_[8];
    #pragma unroll
    for(int u=0;u<8;u++) e_[u] = el[c+u];
    #pragma unroll
    for(int u=0;u<8;u++){
      if(c+u < dg){
        const unsigned short* rp = wb + (size_t)e_[u]*64 + cb;
        uint4 q0 = *(const uint4*)(rp);
        uint4 q1 = *(const uint4*)(rp+32);
        a0[0]+=__uint_as_float(q0.x<<16); a0[1]+=__uint_as_float(q0.x&0xffff0000u);
        a0[2]+=__uint_as_float(q0.y<<16); a0[3]+=__uint_as_float(q0.y&0xffff0000u);
        a0[4]+=__uint_as_float(q0.z<<16); a0[5]+=__uint_as_float(q0.z&0xffff0000u);
        a0[6]+=__uint_as_float(q0.w<<16); a0[7]+=__uint_as_float(q0.w&0xffff0000u);
        a1[0]+=__uint_as_float(q1.x<<16); a1[1]+=__uint_as_float(q1.x&0xffff0000u);
        a1[2]+=__uint_as_float(q1.y<<16); a1[3]+=__uint_as_float(q1.y&0xffff0000u);
        a1[4]+=__uint_as_float(q1.z<<16); a1[5]+=__uint_as_float(q1.z&0xffff0000u);
        a1[6]+=__uint_as_float(q1.w<<16); a1[7]+=__uint_as_float(q1.w&0xffff0000u);
      }
    }
  }
  bf16x8 afU[2];
  #pragma unroll
  for(int u=0;u<8;u++){ afU[0][u]=(short)f2bf(a0[u]); afU[1][u]=(short)f2bf(a1[u]); }
  __syncthreads();

  f32x4 acc[4];
  #pragma unroll
  for(int nt=0;nt<4;nt++) acc[nt] = (f32x4){0.f,0.f,0.f,0.f};
  #pragma unroll
  for(int kt=0;kt<2;kt++){
    #pragma unroll
    for(int nt=0;nt<4;nt++){
      int n = nt*16 + (lane&15);
      bf16x8 bfr = *(const bf16x8*)((const char*)Ush4 + n*128 + ((kt*64 + (lane>>4)*16) ^ ((n&7)<<4)));
      acc[nt] = __builtin_amdgcn_mfma_f32_16x16x32_bf16(afU[kt], bfr, acc[nt], 0,0,0);
    }
  }

  float val[4][4];
  float sum_[4], sq_[4];
  #pragma unroll
  for(int jr=0;jr<4;jr++){ sum_[jr]=0.f; sq_[jr]=0.f; }
  #pragma unroll
  for(int jr=0;jr<4;jr++){
    int nd2 = nb + wid*16 + (lane>>4)*4 + jr;
    #pragma unroll
    for(int nt=0;nt<4;nt++){
      int j = nt*16 + (lane&15);
      float v = acc[nt][jr] + h[(size_t)(b*N_+nd2)*64 + j] + upd_b[k*64 + j];
      val[jr][nt] = v;
      sum_[jr] += v; sq_[jr] += v*v;
    }
  }
  #pragma unroll
  for(int o=1;o<16;o<<=1){
    #pragma unroll
    for(int jr=0;jr<4;jr++){
      sum_[jr] += __shfl_xor(sum_[jr], o, 64);
      sq_[jr]  += __shfl_xor(sq_[jr],  o, 64);
    }
  }
  unsigned short* ysw = Ysh + wid*1024;
  #pragma unroll
  for(int jr=0;jr<4;jr++){
    int rr  = (lane>>4)*4 + jr;
    int nd2 = nb + wid*16 + rr;
    float mean = sum_[jr]*(1.0f/64.0f);
    float var  = sq_[jr]*(1.0f/64.0f) - mean*mean;
    float inv  = rsqrtf(var + EPS_);
    #pragma unroll
    for(int nt=0;nt<4;nt++){
      int j = nt*16 + (lane&15);
      float y = (val[jr][nt] - mean)*inv*ln_g[j] + ln_b[j];
      h[(size_t)(b*N_+nd2)*64 + j] = y;
      if(nd2==0) out[(b*L_+k)*64 + j] = y;
      if(k < L_-1)
        *(unsigned short*)((char*)ysw + rr*128 + ((j*2) ^ ((rr&7)<<4))) = f2bf(y);
    }
  }

  if(k < L_-1){
    f32x4 accw[4];
    #pragma unroll
    for(int nt=0;nt<4;nt++) accw[nt] = (f32x4){0.f,0.f,0.f,0.f};
    #pragma unroll
    for(int kt=0;kt<2;kt++){
      int row = lane&15;
      bf16x8 af = *(const bf16x8*)((const char*)ysw + row*128 + ((kt*64 + (lane>>4)*16) ^ ((row&7)<<4)));
      #pragma unroll
      for(int nt=0;nt<4;nt++){
        int n = nt*16 + (lane&15);
        bf16x8 bfr = *(const bf16x8*)((const char*)Wsh4 + n*128 + ((kt*64 + (lane>>4)*16) ^ ((n&7)<<4)));
        accw[nt] = __builtin_amdgcn_mfma_f32_16x16x32_bf16(af, bfr, accw[nt], 0,0,0);
      }
    }
    #pragma unroll
    for(int jr=0;jr<4;jr++){
      int nd2 = nb + wid*16 + (lane>>4)*4 + jr;
      f32x4 o4;
      #pragma unroll
      for(int nt=0;nt<4;nt++){
        float v = accw[nt][jr] + ((nd2==0) ? w2sum[(k+1)*64 + nt*16 + (lane&15)] : 0.0f);
        o4[nt] = v;
      }
      *(f32x4*)(hW1p + (size_t)(b*N_+nd2)*64 + (lane&15)*4) = o4;
    }
  }
}

extern "C" void kernel_launch(void* const* d_in, const int* in_sizes, int n_in,
                              void* d_out, int out_size, void* d_ws, size_t ws_size,
                              hipStream_t stream) {
  const int*   edge_index = (const int*)d_in[0];
  const int*   rels       = (const int*)d_in[1];
  const float* scores     = (const float*)d_in[2];
  const int*   confm      = (const int*)d_in[3];
  const float* r_query    = (const float*)d_in[6];
  const float* rel_table  = (const float*)d_in[7];
  const float* conf       = (const float*)d_in[8];
  const float* beta_w     = (const float*)d_in[9];
  const float* beta_b     = (const float*)d_in[10];
  const float* msg_w      = (const float*)d_in[11];
  const float* msg_b      = (const float*)d_in[12];
  const float* upd_w      = (const float*)d_in[13];
  const float* upd_b      = (const float*)d_in[14];
  const float* ln_g       = (const float*)d_in[15];
  const float* ln_b       = (const float*)d_in[16];
  float* out = (float*)d_out;

  float* ws      = (float*)d_ws;
  float* h       = ws;
  float* hW1p    = h + B_*N_*D_;
  float* w2sum   = hW1p + B_*N_*D_;
  float* w1sum0  = w2sum + L_*D_;
  float* bdot    = w1sum0 + D_;
  float* qdot    = bdot + 512;
  unsigned short* Btw = (unsigned short*)(qdot + 64);
  unsigned short* Utw = Btw + L_*12288;
  int* deg    = (int*)(Utw + L_*8192);
  int* off    = deg + B_*N_;
  int* cursor = off + B_*N_;
  unsigned short* eidlist = (unsigned short*)(cursor + B_*N_);
  unsigned short* wmsg    = eidlist + B_*E_;
  unsigned short* confp   = wmsg + (size_t)B_*E_*D_;

  size_t need_packed = (size_t)((char*)(confp + (size_t)B_*E_*D_) - (char*)d_ws);
  bool use_packed = ws_size >= need_packed;
  unsigned short* confp_arg = use_packed ? confp : (unsigned short*)nullptr;

  const int setup_total = SEG0 + SEG1 + SEG2 + SEG3 + SEG4 + SEG5;
  k_setup<<<(setup_total+255)/256, 256, 0, stream>>>(rel_table, r_query, beta_w, msg_w, upd_w,
                                                     w2sum, w1sum0, bdot, qdot, Btw, Utw,
                                                     h, hW1p, deg);
  k_hist<<<(B_*E_)/256, 256, 0, stream>>>(edge_index, deg);
  k_scan<<<B_, 1024, 0, stream>>>(deg, off, cursor);
  k_fill<<<(B_*E_)/256, 256, 0, stream>>>(edge_index, cursor, eidlist);

  for(int k=0;k<L_;k++){
    k_edge<<<(B_*E_)/128, 256, 0, stream>>>(edge_index, rels, scores, confm, bdot, qdot,
                                            beta_b, h, rel_table, conf, confp_arg,
                                            Btw, msg_b, hW1p, k, wmsg);
    k_update<<<(B_*N_)/64, 256, 0, stream>>>(wmsg, off, deg, eidlist, Utw, upd_b,
                                             ln_g, ln_b, w2sum, k, h, hW1p, out);
  }
}

// Round 20
// 176.747 us; speedup vs baseline: 1.3114x; 1.3114x over previous
//
#include <hip/hip_runtime.h>

#define B_ 8
#define E_ 32768
#define N_ 4096
#define D_ 64
#define R_ 500
#define L_ 3
#define EPS_ 1e-5f

#define SEG0 256
#define SEG1 ((R_+B_)*64)
#define SEG2 (L_*12288)
#define SEG3 (L_*8192)
#define SEG4 (B_*N_*D_)
#define SEG5 (2*B_*N_)

typedef short bf16x8 __attribute__((ext_vector_type(8)));
typedef float f32x4 __attribute__((ext_vector_type(4)));

__device__ __forceinline__ float sigm(float x){ return 1.0f/(1.0f+__expf(-x)); }
__device__ __forceinline__ unsigned short f2bf(float x){
  unsigned u = __float_as_uint(x);
  u += 0x7fffu + ((u>>16)&1u);
  return (unsigned short)(u>>16);
}
__device__ __forceinline__ bf16x8 pk8(float4 a0, float4 a1, float4 b0, float4 b1){
  bf16x8 v;
  v[0]=(short)f2bf(a0.x*b0.x); v[1]=(short)f2bf(a0.y*b0.y);
  v[2]=(short)f2bf(a0.z*b0.z); v[3]=(short)f2bf(a0.w*b0.w);
  v[4]=(short)f2bf(a1.x*b1.x); v[5]=(short)f2bf(a1.y*b1.y);
  v[6]=(short)f2bf(a1.z*b1.z); v[7]=(short)f2bf(a1.w*b1.w);
  return v;
}
__device__ __forceinline__ bf16x8 cv8(float4 a0, float4 a1){
  bf16x8 v;
  v[0]=(short)f2bf(a0.x); v[1]=(short)f2bf(a0.y); v[2]=(short)f2bf(a0.z); v[3]=(short)f2bf(a0.w);
  v[4]=(short)f2bf(a1.x); v[5]=(short)f2bf(a1.y); v[6]=(short)f2bf(a1.z); v[7]=(short)f2bf(a1.w);
  return v;
}

// ONE fused setup launch: w2sum/w1sum0 | betadot | Btw | Utw | h+hW1p init | deg zero.
__global__ void k_setup(const float* __restrict__ rel_table, const float* __restrict__ r_query,
                        const float* __restrict__ beta_w, const float* __restrict__ msg_w,
                        const float* __restrict__ upd_w,
                        float* __restrict__ w2sum, float* __restrict__ w1sum0,
                        float* __restrict__ bdot, float* __restrict__ qdot,
                        unsigned short* __restrict__ Btw, unsigned short* __restrict__ Utw,
                        float* __restrict__ h, float* __restrict__ hW1p,
                        int* __restrict__ degzero){
  int t = blockIdx.x*256 + threadIdx.x;
  if(t < SEG0){
    int wv = t >> 6, j = t & 63;
    if(wv < 3){
      const float* W2 = msg_w + wv*5*D_*D_ + 2*D_*D_;
      float s = 0.f;
      #pragma unroll
      for(int i=0;i<D_;i++) s += W2[i*D_+j];
      w2sum[wv*D_+j] = s;
    } else {
      const float* W1 = msg_w + 1*D_*D_;
      float s = 0.f;
      #pragma unroll
      for(int i=0;i<D_;i++) s += W1[i*D_+j];
      w1sum0[j] = s;
    }
    return;
  }
  t -= SEG0;
  if(t < SEG1){
    int item = t >> 6, j = t & 63;
    float x = (item < R_ ? rel_table[item*D_+j] : r_query[(item-R_)*D_+j]) * beta_w[j];
    #pragma unroll
    for(int off=32; off; off>>=1) x += __shfl_xor(x, off, 64);
    if(j==0){ if(item < R_) bdot[item] = x; else qdot[item-R_] = x; }
    return;
  }
  t -= SEG1;
  if(t < SEG2){
    int k = t / 12288, rem = t % 12288;
    int n = rem / 192, kk = rem % 192;
    const float* W0 = msg_w + k*5*D_*D_;
    float v = (kk<64)  ? W0[kk*64+n]
            : (kk<128) ? W0[4*D_*D_ + (kk-64)*64+n]      // W4
            :            W0[3*D_*D_ + (kk-128)*64+n];    // W3
    *(unsigned short*)((char*)Btw + k*24576 + n*384 + ((kk*2) ^ ((n&7)<<4))) = f2bf(v);
    return;
  }
  t -= SEG2;
  if(t < SEG3){
    int k = t >> 13, rem = t & 8191;
    int sel = rem >> 12, idx = rem & 4095;
    int n = idx >> 6, kk = idx & 63;
    float v;
    if(sel==0){
      int jsrc = (kk>>2) + (kk&3)*16;
      v = upd_w[k*D_*D_ + jsrc*64 + n];
    } else {
      v = (k < L_-1) ? msg_w[(k+1)*5*D_*D_ + D_*D_ + kk*64 + n] : 0.f;
    }
    *(unsigned short*)((char*)Utw + k*16384 + sel*8192 + n*128 + ((kk*2) ^ ((n&7)<<4))) = f2bf(v);
    return;
  }
  t -= SEG3;
  if(t < SEG4){
    int n = (t / D_) & (N_-1);
    int p = t & (D_-1);
    bool z = (n==0);
    h[t] = z ? 1.0f : 0.0f;
    float hv = 0.0f;
    if(z){
      int j = (p>>2) + (p&3)*16;
      const float* W1 = msg_w + 1*D_*D_;
      const float* W2 = msg_w + 2*D_*D_;
      float s1 = 0.f, s2 = 0.f;
      #pragma unroll
      for(int i=0;i<D_;i++){ s1 += W1[i*D_+j]; s2 += W2[i*D_+j]; }
      hv = s1 + s2;
    }
    hW1p[t] = hv;
    return;
  }
  t -= SEG4;
  if(t < SEG5) degzero[t] = 0;
}

// CSR build (tgt)
__global__ void k_hist(const int* __restrict__ edge_index, int* __restrict__ deg){
  int idx = blockIdx.x*256 + threadIdx.x;
  int b = idx >> 15, e = idx & (E_-1);
  int tgt = edge_index[b*2*E_ + E_ + e];
  atomicAdd(&deg[b*N_ + tgt], 1);
}
__global__ void k_scan(const int* __restrict__ deg, int* __restrict__ off,
                       int* __restrict__ cursor){
  int blk = blockIdx.x, t = threadIdx.x;
  int base = blk*N_ + t*4;
  int v0 = deg[base], v1 = deg[base+1], v2 = deg[base+2], v3 = deg[base+3];
  int s = v0+v1+v2+v3;
  int lane = t & 63, w = t >> 6;
  int x = s;
  #pragma unroll
  for(int d=1; d<64; d<<=1){
    int y = __shfl_up(x, d, 64);
    if(lane >= d) x += y;
  }
  int wave_excl = x - s;
  __shared__ int wsum[16];
  if(lane==63) wsum[w] = x;
  __syncthreads();
  int wbase = 0;
  for(int i=0;i<w;i++) wbase += wsum[i];
  int excl = wbase + wave_excl;
  off[base]   = excl;           cursor[base]   = excl;
  off[base+1] = excl+v0;        cursor[base+1] = excl+v0;
  off[base+2] = excl+v0+v1;     cursor[base+2] = excl+v0+v1;
  off[base+3] = excl+v0+v1+v2;  cursor[base+3] = excl+v0+v1+v2;
}
__global__ void k_fill(const int* __restrict__ edge_index, int* __restrict__ cursor,
                       unsigned short* __restrict__ eidlist){
  int idx = blockIdx.x*256 + threadIdx.x;
  int b = idx >> 15, e = idx & (E_-1);
  int tgt = edge_index[b*2*E_ + E_ + e];
  int pos = atomicAdd(&cursor[b*N_ + tgt], 1);
  eidlist[b*E_ + pos] = (unsigned short)e;
}

// MFMA edge kernel (R18 exact: launch_bounds(256,4), VGPR 64, ~50 µs). conf handling:
//   k==0 & confp: read f32 conf, convert, USE, and store packed fragments to confp
//   k>0  & confp: read packed fragments
//   no confp:     read f32 conf every layer
__global__ void __launch_bounds__(256,4) k_edge(
    const int* __restrict__ edge_index, const int* __restrict__ rels,
    const float* __restrict__ scores, const int* __restrict__ confm,
    const float* __restrict__ bdot, const float* __restrict__ qdot,
    const float* __restrict__ beta_b,
    const float* __restrict__ h, const float* __restrict__ rel_table,
    const float* __restrict__ conf, unsigned short* __restrict__ confp,
    const unsigned short* __restrict__ Btw, const float* __restrict__ msg_b,
    const float* __restrict__ hW1p, int k, unsigned short* __restrict__ wmsg){
  __shared__ __align__(16) uint4 Bsh4[1536];     // 24 KB

  const int tid = threadIdx.x, wid = tid>>6, lane = tid&63;
  const int b     = blockIdx.x & 7;              // XCD-affine batch
  const int chunk = blockIdx.x >> 3;
  const int ein_b = chunk*128 + wid*32;
  const int ebase = b*E_ + ein_b;
  const int ein   = ein_b + (lane&31);
  const int eg    = b*E_ + ein;

  {
    const uint4* src = (const uint4*)((const char*)Btw + k*24576);
    #pragma unroll
    for(int i=0;i<6;i++) Bsh4[i*256+tid] = src[i*256+tid];
  }

  int   srcv = edge_index[b*2*E_ + ein];
  int   relv = rels[eg];
  float beta = sigm(bdot[relv] + qdot[b] + beta_b[0]);
  float gv   = (confm[eg]!=0) ? sigm((scores[eg]-beta)*10.0f) : 0.5f;

  int s_m[2], r_m[2];
  #pragma unroll
  for(int mt=0;mt<2;mt++){
    s_m[mt] = __shfl(srcv, mt*16 + (lane&15));
    r_m[mt] = __shfl(relv, mt*16 + (lane&15));
  }

  bf16x8 af0[2], ar0[2];
  #pragma unroll
  for(int mt=0;mt<2;mt++){
    const float* hp = h + (size_t)(b*N_+s_m[mt])*64 + (lane>>4)*8;
    const float* rp = rel_table + (size_t)r_m[mt]*64 + (lane>>4)*8;
    float4 h0 = *(const float4*)hp, h1 = *(const float4*)(hp+4);
    float4 r0 = *(const float4*)rp, r1 = *(const float4*)(rp+4);
    af0[mt] = pk8(h0, h1, r0, r1);
    ar0[mt] = cv8(r0, r1);
  }

  // conf fragments
  bf16x8 af2[2][2];
  const int half = (ebase>>5)&1;
  uint4* cp = confp ? ((uint4*)confp + (size_t)(ebase>>6)*8*64) : (uint4*)nullptr;
  if(confp && k > 0){
    #pragma unroll
    for(int mt=0;mt<2;mt++)
      #pragma unroll
      for(int kt2=0;kt2<2;kt2++)
        af2[mt][kt2] = *(const bf16x8*)((const uint4*)cp + ((half*2+mt)*2+kt2)*64 + lane);
  } else {
    const float* cb = conf + (size_t)ebase*64;
    #pragma unroll
    for(int mt=0;mt<2;mt++)
      #pragma unroll
      for(int kt2=0;kt2<2;kt2++){
        const float* src = cb + (size_t)(mt*16 + (lane&15))*64 + kt2*32 + (lane>>4)*8;
        af2[mt][kt2] = cv8(*(const float4*)src, *(const float4*)(src+4));
      }
    if(confp){                                   // k==0: publish packed fragments for k=1,2
      #pragma unroll
      for(int mt=0;mt<2;mt++)
        #pragma unroll
        for(int kt2=0;kt2<2;kt2++)
          cp[((half*2+mt)*2+kt2)*64 + lane] = *(const uint4*)&af2[mt][kt2];
    }
  }
  __syncthreads();

  f32x4 acc[2][4];
  #pragma unroll
  for(int mt=0;mt<2;mt++)
    #pragma unroll
    for(int nt=0;nt<4;nt++) acc[mt][nt] = (f32x4){0.f,0.f,0.f,0.f};

  bf16x8 af1[2], ar1[2];
  {
    bf16x8 bfr[4];
    int kbyte = (lane>>4)*16;
    #pragma unroll
    for(int nt=0;nt<4;nt++){
      int n = nt*16 + (lane&15);
      bfr[nt] = *(const bf16x8*)((const char*)Bsh4 + n*384 + (kbyte ^ ((n&7)<<4)));
    }
    #pragma unroll
    for(int mt=0;mt<2;mt++){
      const float* hp = h + (size_t)(b*N_+s_m[mt])*64 + 32 + (lane>>4)*8;
      const float* rp = rel_table + (size_t)r_m[mt]*64 + 32 + (lane>>4)*8;
      float4 h0 = *(const float4*)hp, h1 = *(const float4*)(hp+4);
      float4 r0 = *(const float4*)rp, r1 = *(const float4*)(rp+4);
      af1[mt] = pk8(h0, h1, r0, r1);
      ar1[mt] = cv8(r0, r1);
    }
    #pragma unroll
    for(int mt=0;mt<2;mt++)
      #pragma unroll
      for(int nt=0;nt<4;nt++)
        acc[mt][nt] = __builtin_amdgcn_mfma_f32_16x16x32_bf16(af0[mt], bfr[nt], acc[mt][nt], 0,0,0);
  }
  {
    bf16x8 bfr[4];
    int kbyte = 64 + (lane>>4)*16;
    #pragma unroll
    for(int nt=0;nt<4;nt++){
      int n = nt*16 + (lane&15);
      bfr[nt] = *(const bf16x8*)((const char*)Bsh4 + n*384 + (kbyte ^ ((n&7)<<4)));
    }
    #pragma unroll
    for(int mt=0;mt<2;mt++)
      #pragma unroll
      for(int nt=0;nt<4;nt++)
        acc[mt][nt] = __builtin_amdgcn_mfma_f32_16x16x32_bf16(af1[mt], bfr[nt], acc[mt][nt], 0,0,0);
  }
  #pragma unroll
  for(int kt2=0;kt2<2;kt2++){
    bf16x8 bfr[4];
    int kbyte = 128 + kt2*64 + (lane>>4)*16;
    #pragma unroll
    for(int nt=0;nt<4;nt++){
      int n = nt*16 + (lane&15);
      bfr[nt] = *(const bf16x8*)((const char*)Bsh4 + n*384 + (kbyte ^ ((n&7)<<4)));
    }
    #pragma unroll
    for(int mt=0;mt<2;mt++)
      #pragma unroll
      for(int nt=0;nt<4;nt++)
        acc[mt][nt] = __builtin_amdgcn_mfma_f32_16x16x32_bf16(af2[mt][kt2], bfr[nt], acc[mt][nt], 0,0,0);
  }
  #pragma unroll
  for(int kt3=0;kt3<2;kt3++){
    bf16x8 bfr[4];
    int kbyte = 256 + kt3*64 + (lane>>4)*16;
    #pragma unroll
    for(int nt=0;nt<4;nt++){
      int n = nt*16 + (lane&15);
      bfr[nt] = *(const bf16x8*)((const char*)Bsh4 + n*384 + (kbyte ^ ((n&7)<<4)));
    }
    #pragma unroll
    for(int mt=0;mt<2;mt++)
      #pragma unroll
      for(int nt=0;nt<4;nt++)
        acc[mt][nt] = __builtin_amdgcn_mfma_f32_16x16x32_bf16(kt3 ? ar1[mt] : ar0[mt], bfr[nt], acc[mt][nt], 0,0,0);
  }

  float mb[4];
  #pragma unroll
  for(int nt=0;nt<4;nt++) mb[nt] = msg_b[k*64 + nt*16 + (lane&15)];
  #pragma unroll
  for(int mt=0;mt<2;mt++){
    #pragma unroll
    for(int jr=0;jr<4;jr++){
      int eloc  = mt*16 + (lane>>4)*4 + jr;
      int src_e = __shfl(srcv, eloc);
      float g_e = __shfl(gv,   eloc);
      f32x4 hw = *(const f32x4*)(hW1p + (size_t)(b*N_+src_e)*64 + (lane&15)*4);
      union { unsigned short s[4]; unsigned long long q; } o;
      #pragma unroll
      for(int nt=0;nt<4;nt++){
        float v = acc[mt][nt][jr] + hw[nt] + mb[nt];
        v = fmaxf(v, 0.f) * g_e;
        o.s[nt] = f2bf(v);
      }
      *(unsigned long long*)(wmsg + (size_t)(ebase+eloc)*64 + (lane&15)*4) = o.q;
    }
  }
}

// MFMA node update (R18 exact: launch_bounds(256,2))
__global__ void __launch_bounds__(256,2) k_update(
    const unsigned short* __restrict__ wmsg,
    const int* __restrict__ off, const int* __restrict__ deg,
    const unsigned short* __restrict__ eidlist,
    const unsigned short* __restrict__ Utw,
    const float* __restrict__ upd_b, const float* __restrict__ ln_g,
    const float* __restrict__ ln_b, const float* __restrict__ w2sum,
    int k, float* __restrict__ h, float* __restrict__ hW1p,
    float* __restrict__ out){
  __shared__ __align__(16) uint4 Ush4[512];
  __shared__ __align__(16) uint4 Wsh4[512];
  __shared__ __align__(16) unsigned short Ysh[4*1024];

  const int tid = threadIdx.x, wid = tid>>6, lane = tid&63;
  const int b  = blockIdx.x & 7;
  const int nb = (blockIdx.x >> 3) * 64;

  {
    const uint4* src = (const uint4*)((const char*)Utw + (size_t)k*16384);
    Ush4[tid]     = src[tid];
    Ush4[256+tid] = src[256+tid];
    Wsh4[tid]     = src[512+tid];
    Wsh4[256+tid] = src[768+tid];
  }

  const int nd    = nb + wid*16 + (lane&15);
  const int cbase = b*N_ + nd;
  int o0 = off[cbase], dg = deg[cbase];
  int mdg = dg;
  #pragma unroll
  for(int o=1;o<16;o<<=1) mdg = max(mdg, __shfl_xor(mdg, o, 64));

  const unsigned short* el = eidlist + b*E_ + o0;
  const unsigned short* wb = wmsg + (size_t)b*E_*64;
  const int cb = (lane>>4)*8;

  float a0[8], a1[8];
  #pragma unroll
  for(int u=0;u<8;u++){ a0[u]=0.f; a1[u]=0.f; }

  for(int c=0; c<mdg; c+=8){
    int e_[8];
    #pragma unroll
    for(int u=0;u<8;u++) e_[u] = el[c+u];
    #pragma unroll
    for(int u=0;u<8;u++){
      if(c+u < dg){
        const unsigned short* rp = wb + (size_t)e_[u]*64 + cb;
        uint4 q0 = *(const uint4*)(rp);
        uint4 q1 = *(const uint4*)(rp+32);
        a0[0]+=__uint_as_float(q0.x<<16); a0[1]+=__uint_as_float(q0.x&0xffff0000u);
        a0[2]+=__uint_as_float(q0.y<<16); a0[3]+=__uint_as_float(q0.y&0xffff0000u);
        a0[4]+=__uint_as_float(q0.z<<16); a0[5]+=__uint_as_float(q0.z&0xffff0000u);
        a0[6]+=__uint_as_float(q0.w<<16); a0[7]+=__uint_as_float(q0.w&0xffff0000u);
        a1[0]+=__uint_as_float(q1.x<<16); a1[1]+=__uint_as_float(q1.x&0xffff0000u);
        a1[2]+=__uint_as_float(q1.y<<16); a1[3]+=__uint_as_float(q1.y&0xffff0000u);
        a1[4]+=__uint_as_float(q1.z<<16); a1[5]+=__uint_as_float(q1.z&0xffff0000u);
        a1[6]+=__uint_as_float(q1.w<<16); a1[7]+=__uint_as_float(q1.w&0xffff0000u);
      }
    }
  }
  bf16x8 afU[2];
  #pragma unroll
  for(int u=0;u<8;u++){ afU[0][u]=(short)f2bf(a0[u]); afU[1][u]=(short)f2bf(a1[u]); }
  __syncthreads();

  f32x4 acc[4];
  #pragma unroll
  for(int nt=0;nt<4;nt++) acc[nt] = (f32x4){0.f,0.f,0.f,0.f};
  #pragma unroll
  for(int kt=0;kt<2;kt++){
    #pragma unroll
    for(int nt=0;nt<4;nt++){
      int n = nt*16 + (lane&15);
      bf16x8 bfr = *(const bf16x8*)((const char*)Ush4 + n*128 + ((kt*64 + (lane>>4)*16) ^ ((n&7)<<4)));
      acc[nt] = __builtin_amdgcn_mfma_f32_16x16x32_bf16(afU[kt], bfr, acc[nt], 0,0,0);
    }
  }

  float val[4][4];
  float sum_[4], sq_[4];
  #pragma unroll
  for(int jr=0;jr<4;jr++){ sum_[jr]=0.f; sq_[jr]=0.f; }
  #pragma unroll
  for(int jr=0;jr<4;jr++){
    int nd2 = nb + wid*16 + (lane>>4)*4 + jr;
    #pragma unroll
    for(int nt=0;nt<4;nt++){
      int j = nt*16 + (lane&15);
      float v = acc[nt][jr] + h[(size_t)(b*N_+nd2)*64 + j] + upd_b[k*64 + j];
      val[jr][nt] = v;
      sum_[jr] += v; sq_[jr] += v*v;
    }
  }
  #pragma unroll
  for(int o=1;o<16;o<<=1){
    #pragma unroll
    for(int jr=0;jr<4;jr++){
      sum_[jr] += __shfl_xor(sum_[jr], o, 64);
      sq_[jr]  += __shfl_xor(sq_[jr],  o, 64);
    }
  }
  unsigned short* ysw = Ysh + wid*1024;
  #pragma unroll
  for(int jr=0;jr<4;jr++){
    int rr  = (lane>>4)*4 + jr;
    int nd2 = nb + wid*16 + rr;
    float mean = sum_[jr]*(1.0f/64.0f);
    float var  = sq_[jr]*(1.0f/64.0f) - mean*mean;
    float inv  = rsqrtf(var + EPS_);
    #pragma unroll
    for(int nt=0;nt<4;nt++){
      int j = nt*16 + (lane&15);
      float y = (val[jr][nt] - mean)*inv*ln_g[j] + ln_b[j];
      h[(size_t)(b*N_+nd2)*64 + j] = y;
      if(nd2==0) out[(b*L_+k)*64 + j] = y;
      if(k < L_-1)
        *(unsigned short*)((char*)ysw + rr*128 + ((j*2) ^ ((rr&7)<<4))) = f2bf(y);
    }
  }

  if(k < L_-1){
    f32x4 accw[4];
    #pragma unroll
    for(int nt=0;nt<4;nt++) accw[nt] = (f32x4){0.f,0.f,0.f,0.f};
    #pragma unroll
    for(int kt=0;kt<2;kt++){
      int row = lane&15;
      bf16x8 af = *(const bf16x8*)((const char*)ysw + row*128 + ((kt*64 + (lane>>4)*16) ^ ((row&7)<<4)));
      #pragma unroll
      for(int nt=0;nt<4;nt++){
        int n = nt*16 + (lane&15);
        bf16x8 bfr = *(const bf16x8*)((const char*)Wsh4 + n*128 + ((kt*64 + (lane>>4)*16) ^ ((n&7)<<4)));
        accw[nt] = __builtin_amdgcn_mfma_f32_16x16x32_bf16(af, bfr, accw[nt], 0,0,0);
      }
    }
    #pragma unroll
    for(int jr=0;jr<4;jr++){
      int nd2 = nb + wid*16 + (lane>>4)*4 + jr;
      f32x4 o4;
      #pragma unroll
      for(int nt=0;nt<4;nt++){
        float v = accw[nt][jr] + ((nd2==0) ? w2sum[(k+1)*64 + nt*16 + (lane&15)] : 0.0f);
        o4[nt] = v;
      }
      *(f32x4*)(hW1p + (size_t)(b*N_+nd2)*64 + (lane&15)*4) = o4;
    }
  }
}

extern "C" void kernel_launch(void* const* d_in, const int* in_sizes, int n_in,
                              void* d_out, int out_size, void* d_ws, size_t ws_size,
                              hipStream_t stream) {
  const int*   edge_index = (const int*)d_in[0];
  const int*   rels       = (const int*)d_in[1];
  const float* scores     = (const float*)d_in[2];
  const int*   confm      = (const int*)d_in[3];
  const float* r_query    = (const float*)d_in[6];
  const float* rel_table  = (const float*)d_in[7];
  const float* conf       = (const float*)d_in[8];
  const float* beta_w     = (const float*)d_in[9];
  const float* beta_b     = (const float*)d_in[10];
  const float* msg_w      = (const float*)d_in[11];
  const float* msg_b      = (const float*)d_in[12];
  const float* upd_w      = (const float*)d_in[13];
  const float* upd_b      = (const float*)d_in[14];
  const float* ln_g       = (const float*)d_in[15];
  const float* ln_b       = (const float*)d_in[16];
  float* out = (float*)d_out;

  float* ws      = (float*)d_ws;
  float* h       = ws;
  float* hW1p    = h + B_*N_*D_;
  float* w2sum   = hW1p + B_*N_*D_;
  float* w1sum0  = w2sum + L_*D_;
  float* bdot    = w1sum0 + D_;
  float* qdot    = bdot + 512;
  unsigned short* Btw = (unsigned short*)(qdot + 64);
  unsigned short* Utw = Btw + L_*12288;
  int* deg    = (int*)(Utw + L_*8192);
  int* off    = deg + B_*N_;
  int* cursor = off + B_*N_;
  unsigned short* eidlist = (unsigned short*)(cursor + B_*N_);
  unsigned short* wmsg    = eidlist + B_*E_;
  unsigned short* confp   = wmsg + (size_t)B_*E_*D_;

  size_t need_packed = (size_t)((char*)(confp + (size_t)B_*E_*D_) - (char*)d_ws);
  bool use_packed = ws_size >= need_packed;
  unsigned short* confp_arg = use_packed ? confp : (unsigned short*)nullptr;

  const int setup_total = SEG0 + SEG1 + SEG2 + SEG3 + SEG4 + SEG5;
  k_setup<<<(setup_total+255)/256, 256, 0, stream>>>(rel_table, r_query, beta_w, msg_w, upd_w,
                                                     w2sum, w1sum0, bdot, qdot, Btw, Utw,
                                                     h, hW1p, deg);
  k_hist<<<(B_*E_)/256, 256, 0, stream>>>(edge_index, deg);
  k_scan<<<B_, 1024, 0, stream>>>(deg, off, cursor);
  k_fill<<<(B_*E_)/256, 256, 0, stream>>>(edge_index, cursor, eidlist);

  for(int k=0;k<L_;k++){
    k_edge<<<(B_*E_)/128, 256, 0, stream>>>(edge_index, rels, scores, confm, bdot, qdot,
                                            beta_b, h, rel_table, conf, confp_arg,
                                            Btw, msg_b, hW1p, k, wmsg);
    k_update<<<(B_*N_)/64, 256, 0, stream>>>(wmsg, off, deg, eidlist, Utw, upd_b,
                                             ln_g, ln_b, w2sum, k, h, hW1p, out);
  }
}